// Round 13
// baseline (5046.205 us; speedup 1.0000x reference)
//
#include <hip/hip_runtime.h>

#define Bb 256
#define Tt 256
#define Dd 64
#define Hh 512
#define BH (Bb*Hh)
#define S1 6                       // h1 export slots (L0 run-ahead 4)

typedef _Float16 half8 __attribute__((ext_vector_type(8)));
typedef float floatx4 __attribute__((ext_vector_type(4)));
typedef unsigned long long u64x2 __attribute__((ext_vector_type(2)));

__device__ __forceinline__ float sigm(float x) { return 1.0f/(1.0f + __expf(-x)); }
__device__ __forceinline__ float tanh_(float x) {
  if (x >  15.0f) return  1.0f;
  if (x < -15.0f) return -1.0f;
  float e = __expf(2.0f*x);
  return (e - 1.0f)/(e + 1.0f);
}

// agent-scope accesses (proven r5-r11): compiler-managed
__device__ __forceinline__ void st_u64(_Float16* p, unsigned long long v) {
  __hip_atomic_store((unsigned long long*)p, v, __ATOMIC_RELAXED, __HIP_MEMORY_SCOPE_AGENT);
}
__device__ __forceinline__ half8 ld_h8(const _Float16* p) {
  u64x2 t;
  t.x = __hip_atomic_load((const unsigned long long*)p,       __ATOMIC_RELAXED, __HIP_MEMORY_SCOPE_AGENT);
  t.y = __hip_atomic_load(((const unsigned long long*)p) + 1, __ATOMIC_RELAXED, __HIP_MEMORY_SCOPE_AGENT);
  return __builtin_bit_cast(half8, t);
}
__device__ __forceinline__ unsigned ld_flag(const unsigned* p) {
  return __hip_atomic_load(p, __ATOMIC_RELAXED, __HIP_MEMORY_SCOPE_AGENT);
}
__device__ __forceinline__ void st_flag(unsigned* p, unsigned v) {
  __hip_atomic_store(p, v, __ATOMIC_RELAXED, __HIP_MEMORY_SCOPE_AGENT);
}
__device__ __forceinline__ unsigned get_xcc() {
  unsigned x;
  asm volatile("s_getreg_b32 %0, hwreg(HW_REG_XCC_ID)" : "=s"(x));
  return x & 0xfu;
}

// ---- batched loads: ALL issued, ONE wait, inside ONE asm (r11-proven) ----
// A = address operand placeholder string ("%16" for 16-out, "%32"/"%33" for 32-out)
#define LD16(F,A) \
    "global_load_dwordx4 %0, " A ", off " F "\n\t" \
    "global_load_dwordx4 %1, " A ", off offset:64 " F "\n\t" \
    "global_load_dwordx4 %2, " A ", off offset:128 " F "\n\t" \
    "global_load_dwordx4 %3, " A ", off offset:192 " F "\n\t" \
    "global_load_dwordx4 %4, " A ", off offset:256 " F "\n\t" \
    "global_load_dwordx4 %5, " A ", off offset:320 " F "\n\t" \
    "global_load_dwordx4 %6, " A ", off offset:384 " F "\n\t" \
    "global_load_dwordx4 %7, " A ", off offset:448 " F "\n\t" \
    "global_load_dwordx4 %8, " A ", off offset:512 " F "\n\t" \
    "global_load_dwordx4 %9, " A ", off offset:576 " F "\n\t" \
    "global_load_dwordx4 %10, " A ", off offset:640 " F "\n\t" \
    "global_load_dwordx4 %11, " A ", off offset:704 " F "\n\t" \
    "global_load_dwordx4 %12, " A ", off offset:768 " F "\n\t" \
    "global_load_dwordx4 %13, " A ", off offset:832 " F "\n\t" \
    "global_load_dwordx4 %14, " A ", off offset:896 " F "\n\t" \
    "global_load_dwordx4 %15, " A ", off offset:960 " F "\n\t"
#define LD16B(F,A) \
    "global_load_dwordx4 %16, " A ", off " F "\n\t" \
    "global_load_dwordx4 %17, " A ", off offset:64 " F "\n\t" \
    "global_load_dwordx4 %18, " A ", off offset:128 " F "\n\t" \
    "global_load_dwordx4 %19, " A ", off offset:192 " F "\n\t" \
    "global_load_dwordx4 %20, " A ", off offset:256 " F "\n\t" \
    "global_load_dwordx4 %21, " A ", off offset:320 " F "\n\t" \
    "global_load_dwordx4 %22, " A ", off offset:384 " F "\n\t" \
    "global_load_dwordx4 %23, " A ", off offset:448 " F "\n\t" \
    "global_load_dwordx4 %24, " A ", off offset:512 " F "\n\t" \
    "global_load_dwordx4 %25, " A ", off offset:576 " F "\n\t" \
    "global_load_dwordx4 %26, " A ", off offset:640 " F "\n\t" \
    "global_load_dwordx4 %27, " A ", off offset:704 " F "\n\t" \
    "global_load_dwordx4 %28, " A ", off offset:768 " F "\n\t" \
    "global_load_dwordx4 %29, " A ", off offset:832 " F "\n\t" \
    "global_load_dwordx4 %30, " A ", off offset:896 " F "\n\t" \
    "global_load_dwordx4 %31, " A ", off offset:960 " F "\n\t"
#define LD16OUT(o) \
      "=&v"(o[0]),"=&v"(o[1]),"=&v"(o[2]),"=&v"(o[3]), \
      "=&v"(o[4]),"=&v"(o[5]),"=&v"(o[6]),"=&v"(o[7]), \
      "=&v"(o[8]),"=&v"(o[9]),"=&v"(o[10]),"=&v"(o[11]), \
      "=&v"(o[12]),"=&v"(o[13]),"=&v"(o[14]),"=&v"(o[15])

__device__ __forceinline__ void ld16_llc(const _Float16* p, half8 o[16]) {
  asm volatile(LD16("sc0 sc1","%16") "s_waitcnt vmcnt(0)"
    : LD16OUT(o) : "v"(p) : "memory");
}
__device__ __forceinline__ void ld16_l2(const _Float16* p, half8 o[16]) {
  asm volatile(LD16("sc0","%16") "s_waitcnt vmcnt(0)"
    : LD16OUT(o) : "v"(p) : "memory");
}
__device__ __forceinline__ void ld32_llc(const _Float16* pa, const _Float16* pc,
                                         half8 a[16], half8 c[16]) {
  asm volatile(LD16("sc0 sc1","%32") LD16B("sc0 sc1","%33") "s_waitcnt vmcnt(0)"
    : LD16OUT(a), LD16OUT(c) : "v"(pa), "v"(pc) : "memory");
}
__device__ __forceinline__ void ld32_mix(const _Float16* pa, const _Float16* pc,
                                         half8 a[16], half8 c[16]) {
  // a: local (L2/sc0), c: cross export (LLC/sc0 sc1); one overlapping wait
  asm volatile(LD16("sc0","%32") LD16B("sc0 sc1","%33") "s_waitcnt vmcnt(0)"
    : LD16OUT(a), LD16OUT(c) : "v"(pa), "v"(pc) : "memory");
}

// ws (halfs): h1l[2BH] | h1e[S1*BH] | h2l[2BH] | h2e[BH] | flags[768 u32]
// flags: loc[0..255], exp[256..511], xcd table[512..767]
__global__ void init_kernel(unsigned long long* __restrict__ hz,
                            unsigned* __restrict__ flags) {
  const int j0 = blockIdx.x*blockDim.x + threadIdx.x;
  if (j0 < 768) flags[j0] = 0u;
  const int NZ = (5 + S1)*BH/4;
  for (int j = j0; j < NZ; j += gridDim.x*blockDim.x) hz[j] = 0ull;
}

__global__ void __launch_bounds__(256, 1)
lstm_fused(const float* __restrict__ x,      // [B,T,D] fp32
           _Float16* __restrict__ hb,
           unsigned* __restrict__ flags,
           const float* __restrict__ Wih0, const float* __restrict__ Whh0,
           const float* __restrict__ bih0, const float* __restrict__ bhh0,
           const float* __restrict__ Wih1, const float* __restrict__ Whh1,
           const float* __restrict__ bih1, const float* __restrict__ bhh1,
           const float* __restrict__ fcw,  const float* __restrict__ fcb,
           float* __restrict__ out)
{
  extern __shared__ _Float16 lds[];   // 128 KiB W (lane-major frags) + 2 KiB stage
  __shared__ int s_fast;

  const int tid = threadIdx.x;
  const int bid = blockIdx.x;
  const int grp = bid & 7;
  const int lb  = grp >> 2;
  const int rgi = grp & 3;
  const int cgi = bid >> 3;
  const int hc0 = cgi * 16;
  const int r0  = rgi * 64;

  unsigned* const locf = flags + grp*32 + cgi;
  unsigned* const expf = flags + 256 + grp*32 + cgi;

  _Float16* const h1l = hb;
  _Float16* const h1e = hb + 2*BH;
  _Float16* const h2l = hb + (2 + S1)*BH;
  _Float16* const h2e = hb + (4 + S1)*BH;

  // ---- XCD-uniformity handshake (agent-proven, r9 mechanism) ----
  {
    const unsigned xcd = get_xcc();
    if (tid == 0) st_flag(flags + 512 + grp*32 + cgi, 0x100u | xcd);
    if (tid < 32) {
      const unsigned* q = flags + 512 + grp*32 + tid;
      unsigned v;
      while (1) {
        v = ld_flag(q);
        if (__all((int)((v & 0x100u) != 0u))) break;
        __builtin_amdgcn_s_sleep(1);
      }
      if (tid == 0) s_fast = __all((int)((v & 0xffu) == xcd));
    }
    __syncthreads();
  }
  const int fast = s_fast;

  // ---- preload W slice (fp32 -> fp16) into lane-major fragment LDS (proven) ----
  {
    const float* Whh = lb ? Whh1 : Whh0;
    const float* Wih = lb ? Wih1 : Wih0;
    const int Kin = lb ? Hh : Dd;
    const int KT  = Hh + Kin;
    for (int idx = tid; idx < 64*KT; idx += 256) {
      const int gr = idx / KT;
      const int k  = idx - gr*KT;
      const int bt = gr >> 4, s = gr & 15;
      const int gate = (bt & 1)*2 + (s >> 3);
      const int hcc  = (bt >> 1)*8 + (s & 7);
      const int wrow = gate*Hh + hc0 + hcc;
      const float v = (k < Hh) ? Whh[(size_t)wrow*Hh + k]
                               : Wih[(size_t)wrow*Kin + (k - Hh)];
      const int li = (((k >> 5)*4 + bt) << 9) + ((((k >> 3) & 3)*16 + s) << 3) + (k & 7);
      lds[li] = (_Float16)v;
    }
  }
  __syncthreads();

  const int w    = tid >> 6;
  const int lane = tid & 63;
  const int kg   = lane >> 4;
  const int n15  = lane & 15;
  const bool lo  = (n15 < 8);
  const int rowb = r0 + w*16;

  const _Float16* const bfrag = lds + (lane << 3);
  _Float16* const stage = lds + 65536 + w*256;
  const size_t stoff = (size_t)(rowb + (lane >> 2))*Hh + hc0 + (lane & 3)*4;

  const float* bi = lb ? bih1 : bih0;
  const float* bh = lb ? bhh1 : bhh0;
  float biasA[2], biasB[2];
  #pragma unroll
  for (int o = 0; o < 2; ++o) {
    const int hc = hc0 + o*8 + (n15 & 7);
    biasA[o] = lo ? (bi[hc]      + bh[hc])      : (bi[512+hc]  + bh[512+hc]);
    biasB[o] = lo ? (bi[1024+hc] + bh[1024+hc]) : (bi[1536+hc] + bh[1536+hc]);
  }

  float cst[2][4] = {{0.f,0.f,0.f,0.f},{0.f,0.f,0.f,0.f}};

  for (int i = 0; i <= Tt; ++i) {
    const bool active = lb ? (i >= 1) : (i < Tt);
    if (active) {
      // ---- acquire: agent-flag polls (self: loc>=i; L1 cross: exp>=i; L0 guard: loc>=i-4) ----
      if (tid < 64) {
        const int m = tid & 31;
        const bool self = (tid < 32);
        unsigned tgt;
        const unsigned* fp;
        if (self)    { tgt = (unsigned)i; fp = flags + grp*32 + m; }
        else if (lb) { tgt = (unsigned)i; fp = flags + 256 + (grp ^ 4)*32 + m; }
        else         { tgt = (i >= S1) ? (unsigned)(i - (S1 - 2)) : 0u;
                       fp = flags + (grp ^ 4)*32 + m; }
        while (!__all((int)(ld_flag(fp) >= tgt)))
          __builtin_amdgcn_s_sleep(1);
      }
      asm volatile("s_barrier" ::: "memory");
      __builtin_amdgcn_sched_barrier(0);

      floatx4 acc[4] = {};
      half8 a1[16];

      if (lb) {
        const _Float16* ap = h2l + (size_t)((i+1)&1)*BH + (size_t)(rowb + n15)*Hh + 8*kg;
        const _Float16* cp = h1e + (size_t)((i+S1-1)%S1)*BH + (size_t)(rowb + n15)*Hh + 8*kg;
        half8 a2[16];
        if (fast) ld32_mix(ap, cp, a1, a2);
        else      ld32_llc(ap, cp, a1, a2);
        #pragma unroll
        for (int ks = 0; ks < 16; ++ks)
          #pragma unroll
          for (int bt = 0; bt < 4; ++bt)
            acc[bt] = __builtin_amdgcn_mfma_f32_16x16x32_f16(
                        a1[ks], *(const half8*)(bfrag + ((ks*4 + bt) << 9)), acc[bt], 0,0,0);
        #pragma unroll
        for (int ks = 0; ks < 16; ++ks)
          #pragma unroll
          for (int bt = 0; bt < 4; ++bt)
            acc[bt] = __builtin_amdgcn_mfma_f32_16x16x32_f16(
                        a2[ks], *(const half8*)(bfrag + (((16+ks)*4 + bt) << 9)), acc[bt], 0,0,0);
      } else {
        const _Float16* ap = fast
          ? (h1l + (size_t)((i+1)&1)*BH + (size_t)(rowb + n15)*Hh + 8*kg)
          : (h1e + (size_t)((i+S1-1)%S1)*BH + (size_t)(rowb + n15)*Hh + 8*kg);
        const float* xp = x + (((size_t)(rowb + n15)) << 14) + ((size_t)i << 6) + 8*kg;
        const floatx4 xa = *(const floatx4*)(xp);        // x: normal cached
        const floatx4 xb = *(const floatx4*)(xp + 4);
        const floatx4 xc = *(const floatx4*)(xp + 32);
        const floatx4 xd = *(const floatx4*)(xp + 36);
        if (fast) ld16_l2(ap, a1);
        else      ld16_llc(ap, a1);
        half8 a2[2];
        #pragma unroll
        for (int e = 0; e < 4; ++e) {
          a2[0][e] = (_Float16)xa[e]; a2[0][4+e] = (_Float16)xb[e];
          a2[1][e] = (_Float16)xc[e]; a2[1][4+e] = (_Float16)xd[e];
        }
        #pragma unroll
        for (int ks = 0; ks < 16; ++ks)
          #pragma unroll
          for (int bt = 0; bt < 4; ++bt)
            acc[bt] = __builtin_amdgcn_mfma_f32_16x16x32_f16(
                        a1[ks], *(const half8*)(bfrag + ((ks*4 + bt) << 9)), acc[bt], 0,0,0);
        #pragma unroll
        for (int ks = 0; ks < 2; ++ks)
          #pragma unroll
          for (int bt = 0; bt < 4; ++bt)
            acc[bt] = __builtin_amdgcn_mfma_f32_16x16x32_f16(
                        a2[ks], *(const half8*)(bfrag + (((16+ks)*4 + bt) << 9)), acc[bt], 0,0,0);
      }

      // pointwise -> wave-local stage -> packed u64
      #pragma unroll
      for (int o = 0; o < 2; ++o) {
        #pragma unroll
        for (int rr = 0; rr < 4; ++rr) {
          const float pA = acc[2*o][rr]   + biasA[o];
          const float pB = acc[2*o+1][rr] + biasB[o];
          const float v1 = sigm(pA);
          const float v2 = lo ? tanh_(pB) : sigm(pB);
          const float fs  = __shfl_xor(v1, 8, 64);
          const float os_ = __shfl_xor(v2, 8, 64);
          if (lo) {
            const float c = fs * cst[o][rr] + v1 * v2;
            cst[o][rr] = c;
            stage[(kg*4 + rr)*16 + o*8 + (n15 & 7)] = (_Float16)(os_ * tanh_(c));
          }
        }
      }
      asm volatile("s_waitcnt lgkmcnt(0)" ::: "memory");
      __builtin_amdgcn_sched_barrier(0);
      const unsigned long long pk = *(const unsigned long long*)(stage + (lane << 2));

      // ---- stores + counted drain ----
      if (fast) {
        if (!lb) {
          _Float16* lp = h1l + (size_t)(i&1)*BH + stoff;
          _Float16* ep = h1e + (size_t)(i%S1)*BH + stoff;
          // local drained (oldest); export(i) stays in flight -> drained by next
          // iter's vmcnt(1) or the inactive-iter vmcnt(0); expflag=i covers <=i-1.
          asm volatile(
            "global_store_dwordx2 %0, %2, off sc0\n\t"
            "global_store_dwordx2 %1, %2, off sc0 sc1\n\t"
            "s_waitcnt vmcnt(1)"
            :: "v"(lp), "v"(ep), "v"(pk) : "memory");
        } else if (i == Tt) {
          _Float16* lp = h2l + (size_t)(i&1)*BH + stoff;
          _Float16* ep = h2e + stoff;
          asm volatile(
            "global_store_dwordx2 %0, %2, off sc0\n\t"
            "global_store_dwordx2 %1, %2, off sc0 sc1\n\t"
            "s_waitcnt vmcnt(0)"
            :: "v"(lp), "v"(ep), "v"(pk) : "memory");
        } else {
          _Float16* lp = h2l + (size_t)(i&1)*BH + stoff;
          asm volatile(
            "global_store_dwordx2 %0, %1, off sc0\n\t"
            "s_waitcnt vmcnt(0)"
            :: "v"(lp), "v"(pk) : "memory");
        }
      } else {
        if (!lb) st_u64(h1e + (size_t)(i%S1)*BH + stoff, pk);
        else {
          st_u64(h2l + (size_t)(i&1)*BH + stoff, pk);
          if (i == Tt) st_u64(h2e + stoff, pk);
        }
        asm volatile("s_waitcnt vmcnt(0)" ::: "memory");
      }
    } else {
      asm volatile("s_waitcnt vmcnt(0)" ::: "memory");  // inactive: full drain (covers tail exports)
    }

    // ---- release: raw barrier (no implicit drain), publish flags ----
    asm volatile("s_barrier" ::: "memory");
    if (tid == 0) {
      if (fast) {
        st_flag(locf, (unsigned)(i + 1));
        if (!lb) st_flag(expf, (unsigned)i);   // exports <= i-1 drained
      } else {
        st_flag(locf, (unsigned)(i + 1));
        st_flag(expf, (unsigned)(i + 1));
      }
    }
  }

  // ---- tail: full drain, publish completion (covers h2e + last exports) ----
  asm volatile("s_waitcnt vmcnt(0)" ::: "memory");
  __syncthreads();
  if (tid == 0) {
    st_flag(locf, (unsigned)(Tt + 2));
    st_flag(expf, (unsigned)(Tt + 2));
  }

  // ---- FC: out[b] = h2_final[b,:] . fcw + fcb ----
  if (bid == 0) {
    if (tid < 64) {
      const unsigned* f1 = flags + 256 + (4 + (tid >> 5))*32 + (tid & 31);  // groups 4,5
      const unsigned* f2 = f1 + 64;                                          // groups 6,7
      while (1) {
        int ok = (ld_flag(f1) >= (unsigned)(Tt+2)) & (ld_flag(f2) >= (unsigned)(Tt+2));
        if (__all(ok)) break;
        __builtin_amdgcn_s_sleep(1);
      }
    }
    __syncthreads();
    asm volatile("" ::: "memory");
    float acc = fcb[0];
    for (int c = 0; c < 4; ++c) {
      half8 v[16];
      #pragma unroll
      for (int j = 0; j < 16; ++j)
        v[j] = ld_h8(h2e + (size_t)tid*Hh + c*128 + j*8);
      #pragma unroll
      for (int j = 0; j < 16; ++j)
        #pragma unroll
        for (int e = 0; e < 8; ++e)
          acc += (float)v[j][e] * fcw[c*128 + j*8 + e];
    }
    out[tid] = acc;
  }
}

extern "C" void kernel_launch(void* const* d_in, const int* in_sizes, int n_in,
                              void* d_out, int out_size, void* d_ws, size_t ws_size,
                              hipStream_t stream) {
  const float* x    = (const float*)d_in[0];
  const float* Wih0 = (const float*)d_in[1];
  const float* Whh0 = (const float*)d_in[2];
  const float* bih0 = (const float*)d_in[3];
  const float* bhh0 = (const float*)d_in[4];
  const float* Wih1 = (const float*)d_in[5];
  const float* Whh1 = (const float*)d_in[6];
  const float* bih1 = (const float*)d_in[7];
  const float* bhh1 = (const float*)d_in[8];
  const float* fcw  = (const float*)d_in[9];
  const float* fcb  = (const float*)d_in[10];
  float* out = (float*)d_out;

  _Float16* hb    = (_Float16*)d_ws;                          // (5+S1)*BH halfs
  unsigned* flags = (unsigned*)(hb + (size_t)(5 + S1)*BH);    // 3 KiB

  hipFuncSetAttribute((const void*)lstm_fused,
                      hipFuncAttributeMaxDynamicSharedMemorySize, 133120);

  hipLaunchKernelGGL(init_kernel, dim3(512), dim3(256), 0, stream,
                     (unsigned long long*)hb, flags);

  hipLaunchKernelGGL(lstm_fused, dim3(256), dim3(256), 133120, stream,
                     x, hb, flags,
                     Wih0, Whh0, bih0, bhh0, Wih1, Whh1, bih1, bhh1, fcw, fcb, out);
}

// Round 14
// 4420.367 us; speedup vs baseline: 1.1416x; 1.1416x over previous
//
#include <hip/hip_runtime.h>

#define Bb 256
#define Tt 256
#define Dd 64
#define Hh 512
#define BH (Bb*Hh)
#define S1 6                       // h1 slots (L0 run-ahead 4)

typedef _Float16 half8 __attribute__((ext_vector_type(8)));
typedef float floatx4 __attribute__((ext_vector_type(4)));
typedef unsigned long long u64x2 __attribute__((ext_vector_type(2)));

__device__ __forceinline__ float sigm(float x) { return 1.0f/(1.0f + __expf(-x)); }
__device__ __forceinline__ float tanh_(float x) {
  if (x >  15.0f) return  1.0f;
  if (x < -15.0f) return -1.0f;
  float e = __expf(2.0f*x);
  return (e - 1.0f)/(e + 1.0f);
}

// agent-scope accesses (proven r5-r11): write-through to LLC / bypass reads
__device__ __forceinline__ void st_u64(_Float16* p, unsigned long long v) {
  __hip_atomic_store((unsigned long long*)p, v, __ATOMIC_RELAXED, __HIP_MEMORY_SCOPE_AGENT);
}
__device__ __forceinline__ half8 ld_h8(const _Float16* p) {
  u64x2 t;
  t.x = __hip_atomic_load((const unsigned long long*)p,       __ATOMIC_RELAXED, __HIP_MEMORY_SCOPE_AGENT);
  t.y = __hip_atomic_load(((const unsigned long long*)p) + 1, __ATOMIC_RELAXED, __HIP_MEMORY_SCOPE_AGENT);
  return __builtin_bit_cast(half8, t);
}
__device__ __forceinline__ unsigned ld_flag(const unsigned* p) {
  return __hip_atomic_load(p, __ATOMIC_RELAXED, __HIP_MEMORY_SCOPE_AGENT);
}
__device__ __forceinline__ void st_flag(unsigned* p, unsigned v) {
  __hip_atomic_store(p, v, __ATOMIC_RELAXED, __HIP_MEMORY_SCOPE_AGENT);
}

// ---- batched NORMAL-CACHED loads: all issued, ONE wait, inside ONE asm ----
// Post-acquire-fence these are coherent (L1+L2 invalidated) and L2-SHARED
// across the XCD -> 32x dedup of the group's h-slice reads at the LLC.
#define LD16(A) \
    "global_load_dwordx4 %0, " A ", off\n\t" \
    "global_load_dwordx4 %1, " A ", off offset:64\n\t" \
    "global_load_dwordx4 %2, " A ", off offset:128\n\t" \
    "global_load_dwordx4 %3, " A ", off offset:192\n\t" \
    "global_load_dwordx4 %4, " A ", off offset:256\n\t" \
    "global_load_dwordx4 %5, " A ", off offset:320\n\t" \
    "global_load_dwordx4 %6, " A ", off offset:384\n\t" \
    "global_load_dwordx4 %7, " A ", off offset:448\n\t" \
    "global_load_dwordx4 %8, " A ", off offset:512\n\t" \
    "global_load_dwordx4 %9, " A ", off offset:576\n\t" \
    "global_load_dwordx4 %10, " A ", off offset:640\n\t" \
    "global_load_dwordx4 %11, " A ", off offset:704\n\t" \
    "global_load_dwordx4 %12, " A ", off offset:768\n\t" \
    "global_load_dwordx4 %13, " A ", off offset:832\n\t" \
    "global_load_dwordx4 %14, " A ", off offset:896\n\t" \
    "global_load_dwordx4 %15, " A ", off offset:960\n\t"
#define LD16B(A) \
    "global_load_dwordx4 %16, " A ", off\n\t" \
    "global_load_dwordx4 %17, " A ", off offset:64\n\t" \
    "global_load_dwordx4 %18, " A ", off offset:128\n\t" \
    "global_load_dwordx4 %19, " A ", off offset:192\n\t" \
    "global_load_dwordx4 %20, " A ", off offset:256\n\t" \
    "global_load_dwordx4 %21, " A ", off offset:320\n\t" \
    "global_load_dwordx4 %22, " A ", off offset:384\n\t" \
    "global_load_dwordx4 %23, " A ", off offset:448\n\t" \
    "global_load_dwordx4 %24, " A ", off offset:512\n\t" \
    "global_load_dwordx4 %25, " A ", off offset:576\n\t" \
    "global_load_dwordx4 %26, " A ", off offset:640\n\t" \
    "global_load_dwordx4 %27, " A ", off offset:704\n\t" \
    "global_load_dwordx4 %28, " A ", off offset:768\n\t" \
    "global_load_dwordx4 %29, " A ", off offset:832\n\t" \
    "global_load_dwordx4 %30, " A ", off offset:896\n\t" \
    "global_load_dwordx4 %31, " A ", off offset:960\n\t"
#define LD16OUT(o) \
      "=&v"(o[0]),"=&v"(o[1]),"=&v"(o[2]),"=&v"(o[3]), \
      "=&v"(o[4]),"=&v"(o[5]),"=&v"(o[6]),"=&v"(o[7]), \
      "=&v"(o[8]),"=&v"(o[9]),"=&v"(o[10]),"=&v"(o[11]), \
      "=&v"(o[12]),"=&v"(o[13]),"=&v"(o[14]),"=&v"(o[15])

__device__ __forceinline__ void ld16_c(const _Float16* p, half8 o[16]) {
  asm volatile(LD16("%16") "s_waitcnt vmcnt(0)"
    : LD16OUT(o) : "v"(p) : "memory");
}
__device__ __forceinline__ void ld32_c(const _Float16* pa, const _Float16* pc,
                                       half8 a[16], half8 c[16]) {
  asm volatile(LD16("%32") LD16B("%33") "s_waitcnt vmcnt(0)"
    : LD16OUT(a), LD16OUT(c) : "v"(pa), "v"(pc) : "memory");
}

// ws (halfs): h1e[S1*BH] | h2l[2*BH] | h2e[BH] | flags[512 u32]
__global__ void init_kernel(unsigned long long* __restrict__ hz,
                            unsigned* __restrict__ flags) {
  const int j0 = blockIdx.x*blockDim.x + threadIdx.x;
  if (j0 < 512) flags[j0] = 0u;
  const int NZ = (S1 + 3)*BH/4;
  for (int j = j0; j < NZ; j += gridDim.x*blockDim.x) hz[j] = 0ull;
}

__global__ void __launch_bounds__(256, 1)
lstm_fused(const float* __restrict__ x,      // [B,T,D] fp32
           _Float16* __restrict__ hb,
           unsigned* __restrict__ flags,
           const float* __restrict__ Wih0, const float* __restrict__ Whh0,
           const float* __restrict__ bih0, const float* __restrict__ bhh0,
           const float* __restrict__ Wih1, const float* __restrict__ Whh1,
           const float* __restrict__ bih1, const float* __restrict__ bhh1,
           const float* __restrict__ fcw,  const float* __restrict__ fcb,
           float* __restrict__ out)
{
  extern __shared__ _Float16 lds[];   // 128 KiB W (lane-major frags) + 2 KiB stage

  const int tid = threadIdx.x;
  const int bid = blockIdx.x;
  const int grp = bid & 7;            // (layer,rgi) group
  const int lb  = grp >> 2;
  const int rgi = grp & 3;
  const int cgi = bid >> 3;           // 0..31 col-group (16 h-cols)
  const int hc0 = cgi * 16;
  const int r0  = rgi * 64;

  unsigned* const myexp = flags + grp*32 + cgi;

  _Float16* const h1e = hb;
  _Float16* const h2l = hb + S1*BH;
  _Float16* const h2e = hb + (S1 + 2)*BH;

  // ---- preload W slice (fp32 -> fp16) into lane-major fragment LDS (proven) ----
  {
    const float* Whh = lb ? Whh1 : Whh0;
    const float* Wih = lb ? Wih1 : Wih0;
    const int Kin = lb ? Hh : Dd;
    const int KT  = Hh + Kin;
    for (int idx = tid; idx < 64*KT; idx += 256) {
      const int gr = idx / KT;
      const int k  = idx - gr*KT;
      const int bt = gr >> 4, s = gr & 15;
      const int gate = (bt & 1)*2 + (s >> 3);
      const int hcc  = (bt >> 1)*8 + (s & 7);
      const int wrow = gate*Hh + hc0 + hcc;
      const float v = (k < Hh) ? Whh[(size_t)wrow*Hh + k]
                               : Wih[(size_t)wrow*Kin + (k - Hh)];
      const int li = (((k >> 5)*4 + bt) << 9) + ((((k >> 3) & 3)*16 + s) << 3) + (k & 7);
      lds[li] = (_Float16)v;
    }
  }
  __syncthreads();

  const int w    = tid >> 6;
  const int lane = tid & 63;
  const int kg   = lane >> 4;
  const int n15  = lane & 15;
  const bool lo  = (n15 < 8);
  const int rowb = r0 + w*16;

  const _Float16* const bfrag = lds + (lane << 3);   // + (ks*4+bt)*512
  _Float16* const stage = lds + 65536 + w*256;
  const size_t stoff = (size_t)(rowb + (lane >> 2))*Hh + hc0 + (lane & 3)*4;

  const float* bi = lb ? bih1 : bih0;
  const float* bh = lb ? bhh1 : bhh0;
  float biasA[2], biasB[2];
  #pragma unroll
  for (int o = 0; o < 2; ++o) {
    const int hc = hc0 + o*8 + (n15 & 7);
    biasA[o] = lo ? (bi[hc]      + bh[hc])      : (bi[512+hc]  + bh[512+hc]);
    biasB[o] = lo ? (bi[1024+hc] + bh[1024+hc]) : (bi[1536+hc] + bh[1536+hc]);
  }

  float cst[2][4] = {{0.f,0.f,0.f,0.f},{0.f,0.f,0.f,0.f}};

  for (int i = 0; i <= Tt; ++i) {
    const bool active = lb ? (i >= 1) : (i < Tt);
    if (active) {
      // ---- acquire: agent-flag polls (self >= i; cross: L1 needs i, L0 needs i-4) ----
      if (tid < 64) {
        const int m = tid & 31;
        const bool self = (tid < 32);
        unsigned tgt;
        if (self)    tgt = (unsigned)i;
        else if (lb) tgt = (unsigned)i;
        else         tgt = (i >= S1) ? (unsigned)(i - (S1 - 2)) : 0u;
        const unsigned* fp = flags + (self ? grp : (grp ^ 4))*32 + m;
        while (!__all((int)(ld_flag(fp) >= tgt)))
          __builtin_amdgcn_s_sleep(1);
      }
      __syncthreads();
      // invalidate L1+L2 (clean: all h stores are write-through) -> subsequent
      // NORMAL loads fetch fresh from LLC once per XCD and share via L2.
      __builtin_amdgcn_fence(__ATOMIC_ACQUIRE, "agent");
      __builtin_amdgcn_sched_barrier(0);

      floatx4 acc[4] = {};
      half8 a1[16];

      if (lb) {
        const _Float16* ap = h2l + (size_t)((i+1)&1)*BH + (size_t)(rowb + n15)*Hh + 8*kg;
        const _Float16* cp = h1e + (size_t)((i+S1-1)%S1)*BH + (size_t)(rowb + n15)*Hh + 8*kg;
        half8 a2[16];
        ld32_c(ap, cp, a1, a2);           // 32 cached loads, one wait
        #pragma unroll
        for (int ks = 0; ks < 16; ++ks)
          #pragma unroll
          for (int bt = 0; bt < 4; ++bt)
            acc[bt] = __builtin_amdgcn_mfma_f32_16x16x32_f16(
                        a1[ks], *(const half8*)(bfrag + ((ks*4 + bt) << 9)), acc[bt], 0,0,0);
        #pragma unroll
        for (int ks = 0; ks < 16; ++ks)
          #pragma unroll
          for (int bt = 0; bt < 4; ++bt)
            acc[bt] = __builtin_amdgcn_mfma_f32_16x16x32_f16(
                        a2[ks], *(const half8*)(bfrag + (((16+ks)*4 + bt) << 9)), acc[bt], 0,0,0);
      } else {
        const _Float16* ap = h1e + (size_t)((i+S1-1)%S1)*BH + (size_t)(rowb + n15)*Hh + 8*kg;
        const float* xp = x + (((size_t)(rowb + n15)) << 14) + ((size_t)i << 6) + 8*kg;
        const floatx4 xa = *(const floatx4*)(xp);        // x is immutable: cache-safe
        const floatx4 xb = *(const floatx4*)(xp + 4);
        const floatx4 xc = *(const floatx4*)(xp + 32);
        const floatx4 xd = *(const floatx4*)(xp + 36);
        ld16_c(ap, a1);                   // 16 cached loads, one wait
        half8 a2[2];
        #pragma unroll
        for (int e = 0; e < 4; ++e) {
          a2[0][e] = (_Float16)xa[e]; a2[0][4+e] = (_Float16)xb[e];
          a2[1][e] = (_Float16)xc[e]; a2[1][4+e] = (_Float16)xd[e];
        }
        #pragma unroll
        for (int ks = 0; ks < 16; ++ks)
          #pragma unroll
          for (int bt = 0; bt < 4; ++bt)
            acc[bt] = __builtin_amdgcn_mfma_f32_16x16x32_f16(
                        a1[ks], *(const half8*)(bfrag + ((ks*4 + bt) << 9)), acc[bt], 0,0,0);
        #pragma unroll
        for (int ks = 0; ks < 2; ++ks)
          #pragma unroll
          for (int bt = 0; bt < 4; ++bt)
            acc[bt] = __builtin_amdgcn_mfma_f32_16x16x32_f16(
                        a2[ks], *(const half8*)(bfrag + (((16+ks)*4 + bt) << 9)), acc[bt], 0,0,0);
      }

      // pointwise: lanes n15<8 hold i,g; n15>=8 hold f,o (pair via lane^8); stage h
      #pragma unroll
      for (int o = 0; o < 2; ++o) {
        #pragma unroll
        for (int rr = 0; rr < 4; ++rr) {
          const float pA = acc[2*o][rr]   + biasA[o];
          const float pB = acc[2*o+1][rr] + biasB[o];
          const float v1 = sigm(pA);
          const float v2 = lo ? tanh_(pB) : sigm(pB);
          const float fs  = __shfl_xor(v1, 8, 64);
          const float os_ = __shfl_xor(v2, 8, 64);
          if (lo) {
            const float c = fs * cst[o][rr] + v1 * v2;
            cst[o][rr] = c;
            stage[(kg*4 + rr)*16 + o*8 + (n15 & 7)] = (_Float16)(os_ * tanh_(c));
          }
        }
      }
      asm volatile("s_waitcnt lgkmcnt(0)" ::: "memory");
      __builtin_amdgcn_sched_barrier(0);
      const unsigned long long pk = *(const unsigned long long*)(stage + (lane << 2));

      if (!lb) {
        st_u64(h1e + (size_t)(i%S1)*BH + stoff, pk);      // write-through to LLC
      } else {
        st_u64(h2l + (size_t)(i&1)*BH + stoff, pk);
        if (i == Tt) st_u64(h2e + stoff, pk);
      }
    } // active

    // ---- release (every iter, proven): drain, sync, publish epoch ----
    asm volatile("s_waitcnt vmcnt(0)" ::: "memory");
    __syncthreads();
    if (tid == 0) st_flag(myexp, (unsigned)(i + 1));
  }

  // ---- FC: out[b] = h2_final[b,:] . fcw + fcb ----
  if (bid == 0) {
    if (tid < 64) {
      const unsigned* f1 = flags + (4 + (tid >> 5))*32 + (tid & 31);  // groups 4,5
      const unsigned* f2 = f1 + 64;                                    // groups 6,7
      while (1) {
        int ok = (ld_flag(f1) > (unsigned)Tt) & (ld_flag(f2) > (unsigned)Tt);
        if (__all(ok)) break;
        __builtin_amdgcn_s_sleep(1);
      }
    }
    __syncthreads();
    __builtin_amdgcn_fence(__ATOMIC_ACQUIRE, "agent");
    float acc = fcb[0];
    for (int c = 0; c < 4; ++c) {
      half8 v[16];
      #pragma unroll
      for (int j = 0; j < 16; ++j)
        v[j] = ld_h8(h2e + (size_t)tid*Hh + c*128 + j*8);
      #pragma unroll
      for (int j = 0; j < 16; ++j)
        #pragma unroll
        for (int e = 0; e < 8; ++e)
          acc += (float)v[j][e] * fcw[c*128 + j*8 + e];
    }
    out[tid] = acc;
  }
}

extern "C" void kernel_launch(void* const* d_in, const int* in_sizes, int n_in,
                              void* d_out, int out_size, void* d_ws, size_t ws_size,
                              hipStream_t stream) {
  const float* x    = (const float*)d_in[0];
  const float* Wih0 = (const float*)d_in[1];
  const float* Whh0 = (const float*)d_in[2];
  const float* bih0 = (const float*)d_in[3];
  const float* bhh0 = (const float*)d_in[4];
  const float* Wih1 = (const float*)d_in[5];
  const float* Whh1 = (const float*)d_in[6];
  const float* bih1 = (const float*)d_in[7];
  const float* bhh1 = (const float*)d_in[8];
  const float* fcw  = (const float*)d_in[9];
  const float* fcb  = (const float*)d_in[10];
  float* out = (float*)d_out;

  _Float16* hb    = (_Float16*)d_ws;                          // (S1+3)*BH halfs
  unsigned* flags = (unsigned*)(hb + (size_t)(S1 + 3)*BH);    // 2 KiB

  hipFuncSetAttribute((const void*)lstm_fused,
                      hipFuncAttributeMaxDynamicSharedMemorySize, 133120);

  hipLaunchKernelGGL(init_kernel, dim3(512), dim3(256), 0, stream,
                     (unsigned long long*)hb, flags);

  hipLaunchKernelGGL(lstm_fused, dim3(256), dim3(256), 133120, stream,
                     x, hb, flags,
                     Wih0, Whh0, bih0, bhh0, Wih1, Whh1, bih1, bhh1, fcw, fcb, out);
}

// Round 15
// 2394.051 us; speedup vs baseline: 2.1078x; 1.8464x over previous
//
#include <hip/hip_runtime.h>

#define Bb 256
#define Tt 256
#define Dd 64
#define Hh 512
#define BH (Bb*Hh)
#define S1 6                       // h1 slots (L0 run-ahead 4)

typedef _Float16 half8 __attribute__((ext_vector_type(8)));
typedef float floatx4 __attribute__((ext_vector_type(4)));
typedef unsigned long long u64x2 __attribute__((ext_vector_type(2)));

__device__ __forceinline__ float sigm(float x) { return 1.0f/(1.0f + __expf(-x)); }
__device__ __forceinline__ float tanh_(float x) {
  if (x >  15.0f) return  1.0f;
  if (x < -15.0f) return -1.0f;
  float e = __expf(2.0f*x);
  return (e - 1.0f)/(e + 1.0f);
}

// agent-scope coherent accesses (proven r5-r11): compiler-managed
__device__ __forceinline__ void st_u64(_Float16* p, unsigned long long v) {
  __hip_atomic_store((unsigned long long*)p, v, __ATOMIC_RELAXED, __HIP_MEMORY_SCOPE_AGENT);
}
__device__ __forceinline__ half8 ld_h8(const _Float16* p) {
  u64x2 t;
  t.x = __hip_atomic_load((const unsigned long long*)p,       __ATOMIC_RELAXED, __HIP_MEMORY_SCOPE_AGENT);
  t.y = __hip_atomic_load(((const unsigned long long*)p) + 1, __ATOMIC_RELAXED, __HIP_MEMORY_SCOPE_AGENT);
  return __builtin_bit_cast(half8, t);
}
__device__ __forceinline__ unsigned ld_flag(const unsigned* p) {
  return __hip_atomic_load(p, __ATOMIC_RELAXED, __HIP_MEMORY_SCOPE_AGENT);
}
__device__ __forceinline__ void st_flag(unsigned* p, unsigned v) {
  __hip_atomic_store(p, v, __ATOMIC_RELAXED, __HIP_MEMORY_SCOPE_AGENT);
}

// ---- forced-ILP batched loads: ALL issued, ONE wait, inside ONE asm (r11-proven) ----
#define LD16(A) \
    "global_load_dwordx4 %0, " A ", off sc0 sc1\n\t" \
    "global_load_dwordx4 %1, " A ", off offset:64 sc0 sc1\n\t" \
    "global_load_dwordx4 %2, " A ", off offset:128 sc0 sc1\n\t" \
    "global_load_dwordx4 %3, " A ", off offset:192 sc0 sc1\n\t" \
    "global_load_dwordx4 %4, " A ", off offset:256 sc0 sc1\n\t" \
    "global_load_dwordx4 %5, " A ", off offset:320 sc0 sc1\n\t" \
    "global_load_dwordx4 %6, " A ", off offset:384 sc0 sc1\n\t" \
    "global_load_dwordx4 %7, " A ", off offset:448 sc0 sc1\n\t" \
    "global_load_dwordx4 %8, " A ", off offset:512 sc0 sc1\n\t" \
    "global_load_dwordx4 %9, " A ", off offset:576 sc0 sc1\n\t" \
    "global_load_dwordx4 %10, " A ", off offset:640 sc0 sc1\n\t" \
    "global_load_dwordx4 %11, " A ", off offset:704 sc0 sc1\n\t" \
    "global_load_dwordx4 %12, " A ", off offset:768 sc0 sc1\n\t" \
    "global_load_dwordx4 %13, " A ", off offset:832 sc0 sc1\n\t" \
    "global_load_dwordx4 %14, " A ", off offset:896 sc0 sc1\n\t" \
    "global_load_dwordx4 %15, " A ", off offset:960 sc0 sc1\n\t"
#define LD16OUT(o) \
      "=&v"(o[0]),"=&v"(o[1]),"=&v"(o[2]),"=&v"(o[3]), \
      "=&v"(o[4]),"=&v"(o[5]),"=&v"(o[6]),"=&v"(o[7]), \
      "=&v"(o[8]),"=&v"(o[9]),"=&v"(o[10]),"=&v"(o[11]), \
      "=&v"(o[12]),"=&v"(o[13]),"=&v"(o[14]),"=&v"(o[15])

__device__ __forceinline__ void ld16_batch(const _Float16* p, half8 o[16]) {
  asm volatile(LD16("%16") "s_waitcnt vmcnt(0)"
    : LD16OUT(o) : "v"(p) : "memory");
}

// ws (halfs): h1e[S1*BH] | h2l[2*BH] | h2e[BH] | flags[512 u32]
// flags[g*32 + cgi] = epoch flag of block (group g, col-group cgi)
__global__ void init_kernel(unsigned long long* __restrict__ hz,
                            unsigned* __restrict__ flags) {
  const int j0 = blockIdx.x*blockDim.x + threadIdx.x;
  if (j0 < 512) flags[j0] = 0u;
  const int NZ = (S1 + 3)*BH/4;
  for (int j = j0; j < NZ; j += gridDim.x*blockDim.x) hz[j] = 0ull;
}

__global__ void __launch_bounds__(256, 1)
lstm_fused(const float* __restrict__ x,      // [B,T,D] fp32
           _Float16* __restrict__ hb,
           unsigned* __restrict__ flags,
           const float* __restrict__ Wih0, const float* __restrict__ Whh0,
           const float* __restrict__ bih0, const float* __restrict__ bhh0,
           const float* __restrict__ Wih1, const float* __restrict__ Whh1,
           const float* __restrict__ bih1, const float* __restrict__ bhh1,
           const float* __restrict__ fcw,  const float* __restrict__ fcb,
           float* __restrict__ out)
{
  extern __shared__ _Float16 lds[];   // 128 KiB W (lane-major frags) + 2 KiB stage

  const int tid = threadIdx.x;
  const int bid = blockIdx.x;
  const int grp = bid & 7;            // (layer,rgi) group
  const int lb  = grp >> 2;
  const int rgi = grp & 3;
  const int cgi = bid >> 3;           // 0..31 col-group (16 h-cols)
  const int hc0 = cgi * 16;
  const int r0  = rgi * 64;

  unsigned* const myexp = flags + grp*32 + cgi;

  _Float16* const h1e = hb;
  _Float16* const h2l = hb + S1*BH;
  _Float16* const h2e = hb + (S1 + 2)*BH;

  // ---- preload W slice (fp32 -> fp16) into lane-major fragment LDS (proven) ----
  {
    const float* Whh = lb ? Whh1 : Whh0;
    const float* Wih = lb ? Wih1 : Wih0;
    const int Kin = lb ? Hh : Dd;
    const int KT  = Hh + Kin;
    for (int idx = tid; idx < 64*KT; idx += 256) {
      const int gr = idx / KT;
      const int k  = idx - gr*KT;
      const int bt = gr >> 4, s = gr & 15;
      const int gate = (bt & 1)*2 + (s >> 3);
      const int hcc  = (bt >> 1)*8 + (s & 7);
      const int wrow = gate*Hh + hc0 + hcc;
      const float v = (k < Hh) ? Whh[(size_t)wrow*Hh + k]
                               : Wih[(size_t)wrow*Kin + (k - Hh)];
      const int li = (((k >> 5)*4 + bt) << 9) + ((((k >> 3) & 3)*16 + s) << 3) + (k & 7);
      lds[li] = (_Float16)v;
    }
  }
  __syncthreads();

  const int w    = tid >> 6;
  const int lane = tid & 63;
  const int kg   = lane >> 4;
  const int n15  = lane & 15;
  const bool lo  = (n15 < 8);
  const int rowb = r0 + w*16;

  const _Float16* const bfrag = lds + (lane << 3);   // + (ks*4+bt)*512
  _Float16* const stage = lds + 65536 + w*256;
  const size_t stoff = (size_t)(rowb + (lane >> 2))*Hh + hc0 + (lane & 3)*4;
  const size_t rowoff = (size_t)(rowb + n15)*Hh + 8*kg;

  const float* bi = lb ? bih1 : bih0;
  const float* bh = lb ? bhh1 : bhh0;
  float biasA[2], biasB[2];
  #pragma unroll
  for (int o = 0; o < 2; ++o) {
    const int hc = hc0 + o*8 + (n15 & 7);
    biasA[o] = lo ? (bi[hc]      + bh[hc])      : (bi[512+hc]  + bh[512+hc]);
    biasB[o] = lo ? (bi[1024+hc] + bh[1024+hc]) : (bi[1536+hc] + bh[1536+hc]);
  }

  float cst[2][4] = {{0.f,0.f,0.f,0.f},{0.f,0.f,0.f,0.f}};

  for (int i = 0; i <= Tt; ++i) {
    const bool active = lb ? (i >= 1) : (i < Tt);
    if (active) {
      floatx4 acc[4] = {};

      if (lb) {
        // ===== phase A (cross, usually pre-satisfied by L0 run-ahead) =====
        if (tid < 32) {
          const unsigned* fp = flags + (grp ^ 4)*32 + tid;
          while (!__all((int)(ld_flag(fp) >= (unsigned)i)))
            __builtin_amdgcn_s_sleep(1);
        }
        __syncthreads();
        __builtin_amdgcn_sched_barrier(0);
        {
          const _Float16* cp = h1e + (size_t)((i+S1-1)%S1)*BH + rowoff;
          half8 a2[16];
          ld16_batch(cp, a2);
          #pragma unroll
          for (int ks = 0; ks < 16; ++ks)
            #pragma unroll
            for (int bt = 0; bt < 4; ++bt)
              acc[bt] = __builtin_amdgcn_mfma_f32_16x16x32_f16(
                          a2[ks], *(const half8*)(bfrag + (((16+ks)*4 + bt) << 9)), acc[bt], 0,0,0);
        }
        // ===== phase B (self-recurrence: the critical chain) =====
        if (tid < 32) {
          const unsigned* fp = flags + grp*32 + tid;
          while (!__all((int)(ld_flag(fp) >= (unsigned)i)))
            __builtin_amdgcn_s_sleep(1);
        }
        __syncthreads();
        __builtin_amdgcn_sched_barrier(0);
        {
          const _Float16* ap = h2l + (size_t)((i+1)&1)*BH + rowoff;
          half8 a1[16];
          ld16_batch(ap, a1);
          #pragma unroll
          for (int ks = 0; ks < 16; ++ks)
            #pragma unroll
            for (int bt = 0; bt < 4; ++bt)
              acc[bt] = __builtin_amdgcn_mfma_f32_16x16x32_f16(
                          a1[ks], *(const half8*)(bfrag + ((ks*4 + bt) << 9)), acc[bt], 0,0,0);
        }
      } else {
        // x loads issue pre-poll (immutable, cached) and fly during the wait
        const float* xp = x + (((size_t)(rowb + n15)) << 14) + ((size_t)i << 6) + 8*kg;
        const floatx4 xa = *(const floatx4*)(xp);
        const floatx4 xb = *(const floatx4*)(xp + 4);
        const floatx4 xc = *(const floatx4*)(xp + 32);
        const floatx4 xd = *(const floatx4*)(xp + 36);
        // dual poll (self >= i; guard: L1 flags >= i-4)
        if (tid < 64) {
          const int m = tid & 31;
          const bool self = (tid < 32);
          const unsigned tgt = self ? (unsigned)i
                                    : ((i >= S1) ? (unsigned)(i - (S1 - 2)) : 0u);
          const unsigned* fp = flags + (self ? grp : (grp ^ 4))*32 + m;
          while (!__all((int)(ld_flag(fp) >= tgt)))
            __builtin_amdgcn_s_sleep(1);
        }
        __syncthreads();
        __builtin_amdgcn_sched_barrier(0);
        const _Float16* ap = h1e + (size_t)((i+S1-1)%S1)*BH + rowoff;
        half8 a1[16];
        ld16_batch(ap, a1);
        half8 a2[2];
        #pragma unroll
        for (int e = 0; e < 4; ++e) {
          a2[0][e] = (_Float16)xa[e]; a2[0][4+e] = (_Float16)xb[e];
          a2[1][e] = (_Float16)xc[e]; a2[1][4+e] = (_Float16)xd[e];
        }
        #pragma unroll
        for (int ks = 0; ks < 16; ++ks)
          #pragma unroll
          for (int bt = 0; bt < 4; ++bt)
            acc[bt] = __builtin_amdgcn_mfma_f32_16x16x32_f16(
                        a1[ks], *(const half8*)(bfrag + ((ks*4 + bt) << 9)), acc[bt], 0,0,0);
        #pragma unroll
        for (int ks = 0; ks < 2; ++ks)
          #pragma unroll
          for (int bt = 0; bt < 4; ++bt)
            acc[bt] = __builtin_amdgcn_mfma_f32_16x16x32_f16(
                        a2[ks], *(const half8*)(bfrag + (((16+ks)*4 + bt) << 9)), acc[bt], 0,0,0);
      }

      // pointwise: lanes n15<8 hold i,g; n15>=8 hold f,o (pair via lane^8); stage h
      #pragma unroll
      for (int o = 0; o < 2; ++o) {
        #pragma unroll
        for (int rr = 0; rr < 4; ++rr) {
          const float pA = acc[2*o][rr]   + biasA[o];
          const float pB = acc[2*o+1][rr] + biasB[o];
          const float v1 = sigm(pA);
          const float v2 = lo ? tanh_(pB) : sigm(pB);
          const float fs  = __shfl_xor(v1, 8, 64);
          const float os_ = __shfl_xor(v2, 8, 64);
          if (lo) {
            const float c = fs * cst[o][rr] + v1 * v2;
            cst[o][rr] = c;
            stage[(kg*4 + rr)*16 + o*8 + (n15 & 7)] = (_Float16)(os_ * tanh_(c));
          }
        }
      }
      asm volatile("s_waitcnt lgkmcnt(0)" ::: "memory");
      __builtin_amdgcn_sched_barrier(0);
      const unsigned long long pk = *(const unsigned long long*)(stage + (lane << 2));

      if (!lb) {
        st_u64(h1e + (size_t)(i%S1)*BH + stoff, pk);
      } else {
        st_u64(h2l + (size_t)(i&1)*BH + stoff, pk);
        if (i == Tt) st_u64(h2e + stoff, pk);
      }
    } // active

    // ---- release (every iter, proven): drain, sync, publish epoch ----
    asm volatile("s_waitcnt vmcnt(0)" ::: "memory");
    __syncthreads();
    if (tid == 0) st_flag(myexp, (unsigned)(i + 1));
  }

  // ---- FC: out[b] = h2_final[b,:] . fcw + fcb ----
  if (bid == 0) {
    if (tid < 64) {
      const unsigned* f1 = flags + (4 + (tid >> 5))*32 + (tid & 31);  // groups 4,5
      const unsigned* f2 = f1 + 64;                                    // groups 6,7
      while (1) {
        int ok = (ld_flag(f1) > (unsigned)Tt) & (ld_flag(f2) > (unsigned)Tt);
        if (__all(ok)) break;
        __builtin_amdgcn_s_sleep(1);
      }
    }
    __syncthreads();
    asm volatile("" ::: "memory");
    float acc = fcb[0];
    for (int c = 0; c < 4; ++c) {
      half8 v[16];
      #pragma unroll
      for (int j = 0; j < 16; ++j)
        v[j] = ld_h8(h2e + (size_t)tid*Hh + c*128 + j*8);
      #pragma unroll
      for (int j = 0; j < 16; ++j)
        #pragma unroll
        for (int e = 0; e < 8; ++e)
          acc += (float)v[j][e] * fcw[c*128 + j*8 + e];
    }
    out[tid] = acc;
  }
}

extern "C" void kernel_launch(void* const* d_in, const int* in_sizes, int n_in,
                              void* d_out, int out_size, void* d_ws, size_t ws_size,
                              hipStream_t stream) {
  const float* x    = (const float*)d_in[0];
  const float* Wih0 = (const float*)d_in[1];
  const float* Whh0 = (const float*)d_in[2];
  const float* bih0 = (const float*)d_in[3];
  const float* bhh0 = (const float*)d_in[4];
  const float* Wih1 = (const float*)d_in[5];
  const float* Whh1 = (const float*)d_in[6];
  const float* bih1 = (const float*)d_in[7];
  const float* bhh1 = (const float*)d_in[8];
  const float* fcw  = (const float*)d_in[9];
  const float* fcb  = (const float*)d_in[10];
  float* out = (float*)d_out;

  _Float16* hb    = (_Float16*)d_ws;                          // (S1+3)*BH halfs
  unsigned* flags = (unsigned*)(hb + (size_t)(S1 + 3)*BH);    // 2 KiB

  hipFuncSetAttribute((const void*)lstm_fused,
                      hipFuncAttributeMaxDynamicSharedMemorySize, 133120);

  hipLaunchKernelGGL(init_kernel, dim3(512), dim3(256), 0, stream,
                     (unsigned long long*)hb, flags);

  hipLaunchKernelGGL(lstm_fused, dim3(256), dim3(256), 133120, stream,
                     x, hb, flags,
                     Wih0, Whh0, bih0, bhh0, Wih1, Whh1, bih1, bhh1, fcw, fcb, out);
}